// Round 1
// baseline (532.191 us; speedup 1.0000x reference)
//
#include <hip/hip_runtime.h>
#include <stdint.h>

typedef __attribute__((ext_vector_type(4))) int i32x4;

// ---------------------------------------------------------------------------
// Kernel 1: per-row symmetric weight quantization
//   row_scale = max|W_row| / 127 ; Wq = clip(rint(W/scale), -127, 127)
//   wsum = sum(Wq_row)
// One 256-thread block per row (K = 4096 -> 4 float4 chunks per thread).
// ---------------------------------------------------------------------------
__global__ __launch_bounds__(256) void wquant_kernel(
    const float* __restrict__ W, int8_t* __restrict__ Wq,
    float* __restrict__ row_scales, int* __restrict__ wsum_out, int K)
{
    __shared__ float redf[4];
    __shared__ int   redi[4];
    const int row = blockIdx.x;
    const int t = threadIdx.x;
    const float4* Wrow = (const float4*)(W + (size_t)row * K);
    float4 v[4];
    float am = 0.f;
#pragma unroll
    for (int k = 0; k < 4; ++k) {
        v[k] = Wrow[k * 256 + t];
        am = fmaxf(am, fmaxf(fmaxf(fabsf(v[k].x), fabsf(v[k].y)),
                             fmaxf(fabsf(v[k].z), fabsf(v[k].w))));
    }
#pragma unroll
    for (int off = 32; off >= 1; off >>= 1)
        am = fmaxf(am, __shfl_down(am, off));
    if ((t & 63) == 0) redf[t >> 6] = am;
    __syncthreads();
    am = fmaxf(fmaxf(redf[0], redf[1]), fmaxf(redf[2], redf[3]));
    const float scale = am / 127.0f;   // fp32 division: matches np exactly
    const bool ok = scale > 0.f;

    int lsum = 0;
    int* qrow = (int*)(Wq + (size_t)row * K);
#pragma unroll
    for (int k = 0; k < 4; ++k) {
        int q0 = 0, q1 = 0, q2 = 0, q3 = 0;
        if (ok) {
            q0 = (int)fminf(fmaxf(rintf(v[k].x / scale), -127.f), 127.f);
            q1 = (int)fminf(fmaxf(rintf(v[k].y / scale), -127.f), 127.f);
            q2 = (int)fminf(fmaxf(rintf(v[k].z / scale), -127.f), 127.f);
            q3 = (int)fminf(fmaxf(rintf(v[k].w / scale), -127.f), 127.f);
        }
        qrow[k * 256 + t] = (q0 & 255) | ((q1 & 255) << 8) |
                            ((q2 & 255) << 16) | ((q3 & 255) << 24);
        lsum += q0 + q1 + q2 + q3;
    }
#pragma unroll
    for (int off = 32; off >= 1; off >>= 1) lsum += __shfl_down(lsum, off);
    if ((t & 63) == 0) redi[t >> 6] = lsum;
    __syncthreads();
    if (t == 0) {
        wsum_out[row]   = redi[0] + redi[1] + redi[2] + redi[3];
        row_scales[row] = scale;
    }
}

// ---------------------------------------------------------------------------
// Kernel 2: per-token asymmetric activation quantization
//   Xc = clip(X, cmin, cmax); scale=(max-min)/255 (1.0 if <=0);
//   zp = rint(-128 - min/scale); Xq = clip(rint(Xc/scale)+zp, -128, 127)
// One 256-thread block per token row.
// ---------------------------------------------------------------------------
__global__ __launch_bounds__(256) void xquant_kernel(
    const float* __restrict__ X, const float* __restrict__ cmin,
    const float* __restrict__ cmax, int8_t* __restrict__ Xq,
    float* __restrict__ col_scales, float* __restrict__ zps, int K)
{
    __shared__ float redmn[4], redmx[4];
    const int row = blockIdx.x;
    const int t = threadIdx.x;
    const float4* Xrow = (const float4*)(X + (size_t)row * K);
    const float4* lo4 = (const float4*)cmin;
    const float4* hi4 = (const float4*)cmax;
    float4 v[4];
    float mn = 1e30f, mx = -1e30f;
#pragma unroll
    for (int k = 0; k < 4; ++k) {
        float4 x = Xrow[k * 256 + t];
        float4 lo = lo4[k * 256 + t];
        float4 hi = hi4[k * 256 + t];
        x.x = fminf(fmaxf(x.x, lo.x), hi.x);
        x.y = fminf(fmaxf(x.y, lo.y), hi.y);
        x.z = fminf(fmaxf(x.z, lo.z), hi.z);
        x.w = fminf(fmaxf(x.w, lo.w), hi.w);
        v[k] = x;
        mn = fminf(mn, fminf(fminf(x.x, x.y), fminf(x.z, x.w)));
        mx = fmaxf(mx, fmaxf(fmaxf(x.x, x.y), fmaxf(x.z, x.w)));
    }
#pragma unroll
    for (int off = 32; off >= 1; off >>= 1) {
        mn = fminf(mn, __shfl_down(mn, off));
        mx = fmaxf(mx, __shfl_down(mx, off));
    }
    if ((t & 63) == 0) { redmn[t >> 6] = mn; redmx[t >> 6] = mx; }
    __syncthreads();
    mn = fminf(fminf(redmn[0], redmn[1]), fminf(redmn[2], redmn[3]));
    mx = fmaxf(fmaxf(redmx[0], redmx[1]), fmaxf(redmx[2], redmx[3]));
    float scale = (mx - mn) / 255.0f;
    if (!(scale > 0.f)) scale = 1.0f;
    const float zpf = rintf(-128.0f - mn / scale);

    int* qrow = (int*)(Xq + (size_t)row * K);
#pragma unroll
    for (int k = 0; k < 4; ++k) {
        int q0 = (int)fminf(fmaxf(rintf(v[k].x / scale) + zpf, -128.f), 127.f);
        int q1 = (int)fminf(fmaxf(rintf(v[k].y / scale) + zpf, -128.f), 127.f);
        int q2 = (int)fminf(fmaxf(rintf(v[k].z / scale) + zpf, -128.f), 127.f);
        int q3 = (int)fminf(fmaxf(rintf(v[k].w / scale) + zpf, -128.f), 127.f);
        qrow[k * 256 + t] = (q0 & 255) | ((q1 & 255) << 8) |
                            ((q2 & 255) << 16) | ((q3 & 255) << 24);
    }
    if (t == 0) { col_scales[row] = scale; zps[row] = zpf; }
}

// ---------------------------------------------------------------------------
// Kernel 3: int8 GEMM  C[token][out] = Xq @ Wq^T  with fused dequant epilogue
// m97 structure: 128x128 tile, BK=64, 4 waves (2x2), global_load_lds width=16.
// LDS layout [kslot=4][row=128][16B]: linear in thread order for
// global_load_lds AND bank-conflict-free (2-way, free) on ds_read_b128.
// ---------------------------------------------------------------------------
__global__ __launch_bounds__(256, 2) void gemm_i8_kernel(
    const int8_t* __restrict__ Aq,   // [M_tok][K]
    const int8_t* __restrict__ Bq,   // [N_out][K]
    const float* __restrict__ col_scales, const float* __restrict__ zps,
    const int* __restrict__ wsum, const float* __restrict__ row_scales,
    const float* __restrict__ bias, float* __restrict__ out,
    int Nout, int K)
{
    __shared__ uint8_t As[4][128][16];
    __shared__ uint8_t Bs[4][128][16];
    const int t = threadIdx.x;
    const int lane = t & 63;
    const int w = t >> 6;
    const int wr = w >> 1, wc = w & 1;           // 2x2 wave grid
    const int l15 = lane & 15, lhi = lane >> 4;
    const int brow = blockIdx.y, bcol = blockIdx.x;

    i32x4 acc[4][4] = {};

    // staging: thread t loads (tile_row = t&127, kslot = t>>7) + inst-1 at kslot+2
    const int srow = t & 127;
    const int sslot = t >> 7;                     // 0..1
    const int8_t* agp = Aq + (size_t)(brow * 128 + srow) * K + sslot * 16;
    const int8_t* bgp = Bq + (size_t)(bcol * 128 + srow) * K + sslot * 16;
    uint8_t* aL0 = &As[0][0][0] + t * 16;
    uint8_t* bL0 = &Bs[0][0][0] + t * 16;

    // fragment read base: lanes 0-15 -> 16 consecutive rows, kslot = lane>>4
    const i32x4* Ard = (const i32x4*)&As[lhi][wr * 64 + l15][0];
    const i32x4* Brd = (const i32x4*)&Bs[lhi][wc * 64 + l15][0];

    for (int kt = 0; kt < K; kt += 64) {
        __builtin_amdgcn_global_load_lds(
            (const __attribute__((address_space(1))) void*)(agp + kt),
            (__attribute__((address_space(3))) void*)(aL0), 16, 0, 0);
        __builtin_amdgcn_global_load_lds(
            (const __attribute__((address_space(1))) void*)(agp + kt + 32),
            (__attribute__((address_space(3))) void*)(aL0 + 4096), 16, 0, 0);
        __builtin_amdgcn_global_load_lds(
            (const __attribute__((address_space(1))) void*)(bgp + kt),
            (__attribute__((address_space(3))) void*)(bL0), 16, 0, 0);
        __builtin_amdgcn_global_load_lds(
            (const __attribute__((address_space(1))) void*)(bgp + kt + 32),
            (__attribute__((address_space(3))) void*)(bL0 + 4096), 16, 0, 0);
        __syncthreads();   // compiler drains vmcnt before s_barrier

        i32x4 af[4], bf[4];
#pragma unroll
        for (int m = 0; m < 4; ++m) af[m] = Ard[m * 16];   // +16 rows = +256B
#pragma unroll
        for (int n = 0; n < 4; ++n) bf[n] = Brd[n * 16];
#pragma unroll
        for (int m = 0; m < 4; ++m)
#pragma unroll
            for (int n = 0; n < 4; ++n)
                acc[m][n] = __builtin_amdgcn_mfma_i32_16x16x64_i8(
                    af[m], bf[n], acc[m][n], 0, 0, 0);
        __syncthreads();
    }

    // epilogue: Y = (acc - zp*wsum) * cs * rs + bias
    const int trow0 = brow * 128 + wr * 64;
    const int ocol0 = bcol * 128 + wc * 64;
    float rs_[4], bi_[4];
    int ws_[4];
#pragma unroll
    for (int n = 0; n < 4; ++n) {
        const int oc = ocol0 + n * 16 + l15;
        rs_[n] = row_scales[oc];
        bi_[n] = bias[oc];
        ws_[n] = wsum[oc];
    }
#pragma unroll
    for (int m = 0; m < 4; ++m) {
#pragma unroll
        for (int r = 0; r < 4; ++r) {
            const int token = trow0 + m * 16 + lhi * 4 + r;  // C/D: row=(l>>4)*4+r
            const float cs = col_scales[token];
            const int zv = (int)zps[token];
            float* orow = out + (size_t)token * Nout + ocol0;
#pragma unroll
            for (int n = 0; n < 4; ++n) {
                const int a = acc[m][n][r] - zv * ws_[n];
                orow[n * 16 + l15] = (float)a * cs * rs_[n] + bi_[n];
            }
        }
    }
}

// ---------------------------------------------------------------------------
extern "C" void kernel_launch(void* const* d_in, const int* in_sizes, int n_in,
                              void* d_out, int out_size, void* d_ws, size_t ws_size,
                              hipStream_t stream)
{
    const float* x    = (const float*)d_in[0];
    const float* W    = (const float*)d_in[1];
    const float* bias = (const float*)d_in[2];
    const float* cmin = (const float*)d_in[3];
    const float* cmax = (const float*)d_in[4];
    float* out = (float*)d_out;

    const int D_IN  = in_sizes[3];               // 4096
    const int D_OUT = in_sizes[2];               // 4096
    const int Ntok  = in_sizes[0] / D_IN;        // 8192

    uint8_t* ws = (uint8_t*)d_ws;
    int8_t* Wq = (int8_t*)ws;
    int8_t* Xq = (int8_t*)(ws + (size_t)D_OUT * D_IN);
    float* row_scales = (float*)(ws + (size_t)D_OUT * D_IN + (size_t)Ntok * D_IN);
    int*   wsum       = (int*)(row_scales + D_OUT);
    float* col_scales = (float*)(wsum + D_OUT);
    float* zps        = col_scales + Ntok;

    wquant_kernel<<<D_OUT, 256, 0, stream>>>(W, Wq, row_scales, wsum, D_IN);
    xquant_kernel<<<Ntok, 256, 0, stream>>>(x, cmin, cmax, Xq, col_scales, zps, D_IN);

    dim3 grid(D_OUT / 128, Ntok / 128);
    gemm_i8_kernel<<<grid, dim3(256), 0, stream>>>(
        Xq, Wq, col_scales, zps, wsum, row_scales, bias, out, D_OUT, D_IN);
}

// Round 10
// 412.290 us; speedup vs baseline: 1.2908x; 1.2908x over previous
//
#include <hip/hip_runtime.h>
#include <stdint.h>

typedef __attribute__((ext_vector_type(4))) int i32x4;

// ---------------------------------------------------------------------------
// Kernel 1: per-row symmetric weight quantization (unchanged, validated R1)
// ---------------------------------------------------------------------------
__global__ __launch_bounds__(256) void wquant_kernel(
    const float* __restrict__ W, int8_t* __restrict__ Wq,
    float* __restrict__ row_scales, int* __restrict__ wsum_out, int K)
{
    __shared__ float redf[4];
    __shared__ int   redi[4];
    const int row = blockIdx.x;
    const int t = threadIdx.x;
    const float4* Wrow = (const float4*)(W + (size_t)row * K);
    float4 v[4];
    float am = 0.f;
#pragma unroll
    for (int k = 0; k < 4; ++k) {
        v[k] = Wrow[k * 256 + t];
        am = fmaxf(am, fmaxf(fmaxf(fabsf(v[k].x), fabsf(v[k].y)),
                             fmaxf(fabsf(v[k].z), fabsf(v[k].w))));
    }
#pragma unroll
    for (int off = 32; off >= 1; off >>= 1)
        am = fmaxf(am, __shfl_down(am, off));
    if ((t & 63) == 0) redf[t >> 6] = am;
    __syncthreads();
    am = fmaxf(fmaxf(redf[0], redf[1]), fmaxf(redf[2], redf[3]));
    const float scale = am / 127.0f;
    const bool ok = scale > 0.f;

    int lsum = 0;
    int* qrow = (int*)(Wq + (size_t)row * K);
#pragma unroll
    for (int k = 0; k < 4; ++k) {
        int q0 = 0, q1 = 0, q2 = 0, q3 = 0;
        if (ok) {
            q0 = (int)fminf(fmaxf(rintf(v[k].x / scale), -127.f), 127.f);
            q1 = (int)fminf(fmaxf(rintf(v[k].y / scale), -127.f), 127.f);
            q2 = (int)fminf(fmaxf(rintf(v[k].z / scale), -127.f), 127.f);
            q3 = (int)fminf(fmaxf(rintf(v[k].w / scale), -127.f), 127.f);
        }
        qrow[k * 256 + t] = (q0 & 255) | ((q1 & 255) << 8) |
                            ((q2 & 255) << 16) | ((q3 & 255) << 24);
        lsum += q0 + q1 + q2 + q3;
    }
#pragma unroll
    for (int off = 32; off >= 1; off >>= 1) lsum += __shfl_down(lsum, off);
    if ((t & 63) == 0) redi[t >> 6] = lsum;
    __syncthreads();
    if (t == 0) {
        wsum_out[row]   = redi[0] + redi[1] + redi[2] + redi[3];
        row_scales[row] = scale;
    }
}

// ---------------------------------------------------------------------------
// Kernel 2: per-token asymmetric activation quantization (unchanged, R1)
// ---------------------------------------------------------------------------
__global__ __launch_bounds__(256) void xquant_kernel(
    const float* __restrict__ X, const float* __restrict__ cmin,
    const float* __restrict__ cmax, int8_t* __restrict__ Xq,
    float* __restrict__ col_scales, float* __restrict__ zps, int K)
{
    __shared__ float redmn[4], redmx[4];
    const int row = blockIdx.x;
    const int t = threadIdx.x;
    const float4* Xrow = (const float4*)(X + (size_t)row * K);
    const float4* lo4 = (const float4*)cmin;
    const float4* hi4 = (const float4*)cmax;
    float4 v[4];
    float mn = 1e30f, mx = -1e30f;
#pragma unroll
    for (int k = 0; k < 4; ++k) {
        float4 x = Xrow[k * 256 + t];
        float4 lo = lo4[k * 256 + t];
        float4 hi = hi4[k * 256 + t];
        x.x = fminf(fmaxf(x.x, lo.x), hi.x);
        x.y = fminf(fmaxf(x.y, lo.y), hi.y);
        x.z = fminf(fmaxf(x.z, lo.z), hi.z);
        x.w = fminf(fmaxf(x.w, lo.w), hi.w);
        v[k] = x;
        mn = fminf(mn, fminf(fminf(x.x, x.y), fminf(x.z, x.w)));
        mx = fmaxf(mx, fmaxf(fmaxf(x.x, x.y), fmaxf(x.z, x.w)));
    }
#pragma unroll
    for (int off = 32; off >= 1; off >>= 1) {
        mn = fminf(mn, __shfl_down(mn, off));
        mx = fmaxf(mx, __shfl_down(mx, off));
    }
    if ((t & 63) == 0) { redmn[t >> 6] = mn; redmx[t >> 6] = mx; }
    __syncthreads();
    mn = fminf(fminf(redmn[0], redmn[1]), fminf(redmn[2], redmn[3]));
    mx = fmaxf(fmaxf(redmx[0], redmx[1]), fmaxf(redmx[2], redmx[3]));
    float scale = (mx - mn) / 255.0f;
    if (!(scale > 0.f)) scale = 1.0f;
    const float zpf = rintf(-128.0f - mn / scale);

    int* qrow = (int*)(Xq + (size_t)row * K);
#pragma unroll
    for (int k = 0; k < 4; ++k) {
        int q0 = (int)fminf(fmaxf(rintf(v[k].x / scale) + zpf, -128.f), 127.f);
        int q1 = (int)fminf(fmaxf(rintf(v[k].y / scale) + zpf, -128.f), 127.f);
        int q2 = (int)fminf(fmaxf(rintf(v[k].z / scale) + zpf, -128.f), 127.f);
        int q3 = (int)fminf(fmaxf(rintf(v[k].w / scale) + zpf, -128.f), 127.f);
        qrow[k * 256 + t] = (q0 & 255) | ((q1 & 255) << 8) |
                            ((q2 & 255) << 16) | ((q3 & 255) << 24);
    }
    if (t == 0) { col_scales[row] = scale; zps[row] = zpf; }
}

// ---------------------------------------------------------------------------
// Kernel 3: int8 GEMM, 256x256 tile, BK=128 bytes, 8-phase schedule (T3+T4+T5)
// LDS 128KB: buf d @ d*65536; within buf: A0@0, A1@16384, B0@32768, B1@49152.
// Half-tile 16KB = [kslot 0..7][row 0..127][16B]; linear in thread order so
// global_load_lds width-16 stages it directly; fragment reads are 16B-stride
// across lanes -> 0 bank conflicts (measured R1).
// Waves: 8 = 2(M) x 4(N); per-wave out 128x64 as two 64-row strips (one per
// A-half) x two 32-col strips (one per B-half) so each quadrant phase touches
// exactly one A-half and one B-half.
// Stage schedule per iter i (bufA=kt 2i even, bufB=kt 2i+1 odd):
//  ph1:(0,0) stage bufB.A1<-A1(2i+1)   ph5:(0,0)' stage bufA.A1<-A1(2i+2)
//  ph2:(1,0) stage bufB.B1<-B1(2i+1)   ph6:(1,0)' stage bufA.B1<-B1(2i+2)
//  ph3:(0,1) stage bufA.B0<-B0(2i+2)   ph7:(0,1)' stage bufB.B0<-B0(2i+3)
//  ph4:(1,1) stage bufA.A0<-A0(2i+2)   ph8:(1,1)' stage bufB.A0<-A0(2i+3)
//  vmcnt(4) at ph4/ph8 (= last 2 stage-pairs still in flight, never 0).
// FINAL iteration (R3 fix): MUST still stage bufB.A1/B1 <- kLast in ph1/ph2
// (they are consumed by ph6/ph7 of the same iteration); only the kt+2/kt+3
// lookahead stages are dropped; VMW(0) at ph4 drains all 8 outstanding
// before the bufB-reading phases.
// R7 desk-audit: full ledger traced (queue order at every VMW, WAR/RAW
// pairwise across all 8 phases) — consistent; no further static holes.
// R8 desk-audit: compiler-interaction pass (rule-#18 n/a: fragment reads are
// C++ loads so hipcc owns the lgkmcnt deps; epilogue int-cast exact; VGPR
// budget fits 2 waves/SIMD) — clean.
// ---------------------------------------------------------------------------

__device__ __forceinline__ void gload16(const int8_t* g, const uint8_t* l) {
    __builtin_amdgcn_global_load_lds(
        (const __attribute__((address_space(1))) void*)g,
        (__attribute__((address_space(3))) void*)l, 16, 0, 0);
}

__device__ __forceinline__ void bar() {
    asm volatile("" ::: "memory");
    __builtin_amdgcn_s_barrier();
    asm volatile("" ::: "memory");
}

#define VMW(N) asm volatile("s_waitcnt vmcnt(" #N ")" ::: "memory")

#define RD_A(mh, db)                                                          \
    { _Pragma("unroll") for (int f = 0; f < 4; ++f) {                         \
        afr[mh][f][0] = *(const i32x4*)(aRd + (db) + (mh)*16384 + f*256);     \
        afr[mh][f][1] = *(const i32x4*)(aRd + (db) + (mh)*16384 + 8192 + f*256); } }

#define RD_B(nh, db)                                                          \
    { _Pragma("unroll") for (int g = 0; g < 2; ++g) {                         \
        bfr[g][0] = *(const i32x4*)(bRd + (db) + (nh)*16384 + g*256);         \
        bfr[g][1] = *(const i32x4*)(bRd + (db) + (nh)*16384 + 8192 + g*256); } }

#define MM(mh, nh)                                                            \
    { __builtin_amdgcn_s_setprio(1);                                          \
      _Pragma("unroll") for (int f = 0; f < 4; ++f)                           \
      _Pragma("unroll") for (int g = 0; g < 2; ++g) {                         \
        acc[(mh)*4+f][(nh)*2+g] = __builtin_amdgcn_mfma_i32_16x16x64_i8(      \
            afr[mh][f][0], bfr[g][0], acc[(mh)*4+f][(nh)*2+g], 0, 0, 0);      \
        acc[(mh)*4+f][(nh)*2+g] = __builtin_amdgcn_mfma_i32_16x16x64_i8(      \
            afr[mh][f][1], bfr[g][1], acc[(mh)*4+f][(nh)*2+g], 0, 0, 0); }    \
      __builtin_amdgcn_s_setprio(0); }

#define STG_A(db, h, ktv)                                                     \
    { const int8_t* g_ = aSt + (size_t)(h)*128*Ks + (size_t)(ktv)*128;        \
      gload16(g_,      lSt + (db) + (h)*16384);                               \
      gload16(g_ + 64, lSt + (db) + (h)*16384 + 8192); }

#define STG_B(db, h, ktv)                                                     \
    { const int8_t* g_ = bSt + (size_t)(h)*128*Ks + (size_t)(ktv)*128;        \
      gload16(g_,      lSt + (db) + 32768 + (h)*16384);                       \
      gload16(g_ + 64, lSt + (db) + 32768 + (h)*16384 + 8192); }

__global__ __launch_bounds__(512, 2) void gemm_i8_kernel(
    const int8_t* __restrict__ Aq,   // [M_tok][K]
    const int8_t* __restrict__ Bq,   // [N_out][K]
    const float* __restrict__ col_scales, const float* __restrict__ zps,
    const int* __restrict__ wsum, const float* __restrict__ row_scales,
    const float* __restrict__ bias, float* __restrict__ out,
    int Nout, int K)
{
    __shared__ uint8_t lds[131072];
    const int t = threadIdx.x;
    const int lane = t & 63;
    const int w = t >> 6;              // 0..7
    const int wr = w >> 2;             // 0..1  (M)
    const int wc = w & 3;              // 0..3  (N)
    const int l15 = lane & 15, lhi = lane >> 4;
    const size_t Ks = (size_t)K;
    const int aRow0 = blockIdx.y * 256;
    const int bRow0 = blockIdx.x * 256;

    const int8_t* aSt = Aq + (size_t)(aRow0 + (t & 127)) * Ks + ((t >> 7) * 16);
    const int8_t* bSt = Bq + (size_t)(bRow0 + (t & 127)) * Ks + ((t >> 7) * 16);
    const uint8_t* lSt = lds + t * 16;
    const uint8_t* aRd = lds + lhi * 2048 + (wr * 64 + l15) * 16;
    const uint8_t* bRd = lds + 32768 + lhi * 2048 + (wc * 32 + l15) * 16;

    i32x4 acc[8][4] = {};
    i32x4 afr[2][4][2], bfr[2][2];

    // ---- prologue: kt0 all 4 halves -> bufA; kt1 B0,A0 -> bufB ----
    STG_A(0, 0, 0); STG_A(0, 1, 0); STG_B(0, 0, 0); STG_B(0, 1, 0);
    STG_B(65536, 0, 1); STG_A(65536, 0, 1);
    VMW(4);            // bufA's 8 loads landed; bufB's 4 still in flight
    bar();

    const int nit = (K >> 8);          // iterations of 2 K-tiles
    for (int i2 = 0; i2 < nit - 1; ++i2) {
        const int kB1 = 2 * i2 + 1, kA = 2 * i2 + 2, kB3 = 2 * i2 + 3;
        RD_A(0, 0); RD_B(0, 0); STG_A(65536, 1, kB1); bar(); MM(0, 0); bar();
        RD_A(1, 0);             STG_B(65536, 1, kB1); bar(); MM(1, 0); bar();
        RD_B(1, 0);             STG_B(0, 0, kA);      bar(); MM(0, 1); bar();
                                STG_A(0, 0, kA);      bar(); MM(1, 1); VMW(4); bar();
        RD_A(0, 65536); RD_B(0, 65536); STG_A(0, 1, kA); bar(); MM(0, 0); bar();
        RD_A(1, 65536);         STG_B(0, 1, kA);      bar(); MM(1, 0); bar();
        RD_B(1, 65536);         STG_B(65536, 0, kB3); bar(); MM(0, 1); bar();
                                STG_A(65536, 0, kB3); bar(); MM(1, 1); VMW(4); bar();
    }
    // ---- final iteration: still stage bufB.A1/B1 <- kLast (read by ph6/ph7);
    //      drop only the kt+2/kt+3 lookahead stages; full drain at ph4 ----
    {
        const int kLast = 2 * nit - 1;
        RD_A(0, 0); RD_B(0, 0); STG_A(65536, 1, kLast); bar(); MM(0, 0); bar();
        RD_A(1, 0);             STG_B(65536, 1, kLast); bar(); MM(1, 0); bar();
        RD_B(1, 0);             bar(); MM(0, 1); bar();
                                bar(); MM(1, 1); VMW(0); bar();
        RD_A(0, 65536); RD_B(0, 65536); bar(); MM(0, 0); bar();
        RD_A(1, 65536);         bar(); MM(1, 0); bar();
        RD_B(1, 65536);         bar(); MM(0, 1); bar();
                                bar(); MM(1, 1);
    }

    // ---- epilogue: Y = (acc - zp*wsum) * cs * rs + bias ----
    const int ocol0 = bRow0 + wc * 32 + l15;
    float rs_[4], bi_[4];
    int ws_[4];
#pragma unroll
    for (int n = 0; n < 4; ++n) {
        const int oc = ocol0 + (n >> 1) * 128 + (n & 1) * 16;
        rs_[n] = row_scales[oc];
        bi_[n] = bias[oc];
        ws_[n] = wsum[oc];
    }
#pragma unroll
    for (int m = 0; m < 8; ++m) {
        const int trowb = aRow0 + (m >> 2) * 128 + wr * 64 + (m & 3) * 16 + lhi * 4;
#pragma unroll
        for (int r = 0; r < 4; ++r) {
            const int token = trowb + r;                 // C/D: row=(l>>4)*4+reg
            const float cs = col_scales[token];
            const int zv = (int)zps[token];
            float* orow = out + (size_t)token * Nout + ocol0;
#pragma unroll
            for (int n = 0; n < 4; ++n) {
                const int a = acc[m][n][r] - zv * ws_[n];
                orow[(n >> 1) * 128 + (n & 1) * 16] = (float)a * cs * rs_[n] + bi_[n];
            }
        }
    }
}

// ---------------------------------------------------------------------------
extern "C" void kernel_launch(void* const* d_in, const int* in_sizes, int n_in,
                              void* d_out, int out_size, void* d_ws, size_t ws_size,
                              hipStream_t stream)
{
    const float* x    = (const float*)d_in[0];
    const float* W    = (const float*)d_in[1];
    const float* bias = (const float*)d_in[2];
    const float* cmin = (const float*)d_in[3];
    const float* cmax = (const float*)d_in[4];
    float* out = (float*)d_out;

    const int D_IN  = in_sizes[3];               // 4096
    const int D_OUT = in_sizes[2];               // 4096
    const int Ntok  = in_sizes[0] / D_IN;        // 8192

    uint8_t* ws = (uint8_t*)d_ws;
    int8_t* Wq = (int8_t*)ws;
    int8_t* Xq = (int8_t*)(ws + (size_t)D_OUT * D_IN);
    float* row_scales = (float*)(ws + (size_t)D_OUT * D_IN + (size_t)Ntok * D_IN);
    int*   wsum       = (int*)(row_scales + D_OUT);
    float* col_scales = (float*)(wsum + D_OUT);
    float* zps        = col_scales + Ntok;

    wquant_kernel<<<D_OUT, 256, 0, stream>>>(W, Wq, row_scales, wsum, D_IN);
    xquant_kernel<<<Ntok, 256, 0, stream>>>(x, cmin, cmax, Xq, col_scales, zps, D_IN);

    dim3 grid(D_OUT / 256, Ntok / 256);
    gemm_i8_kernel<<<grid, dim3(512), 0, stream>>>(
        Xq, Wq, col_scales, zps, wsum, row_scales, bias, out, D_OUT, D_IN);
}